// Round 13
// baseline (183.047 us; speedup 1.0000x reference)
//
#include <hip/hip_runtime.h>

#define NB  8
#define TOQ 2048
#define TIV 2048
#define HD  128

typedef float f32x4 __attribute__((ext_vector_type(4)));
typedef short s16x8 __attribute__((ext_vector_type(8)));
typedef unsigned short ushort8v __attribute__((ext_vector_type(8)));

__device__ __forceinline__ unsigned short f2bf(float f) {   // RNE f32->bf16
    unsigned u = __float_as_uint(f);
    return (unsigned short)((u + 0x7FFFu + ((u >> 16) & 1u)) >> 16);
}
__device__ __forceinline__ float bf2f(unsigned short h) {
    return __uint_as_float(((unsigned)h) << 16);
}

__device__ __forceinline__ void split8(const float4 a, const float4 b,
                                       ushort8v& h, ushort8v& l) {
    const float x[8] = {a.x, a.y, a.z, a.w, b.x, b.y, b.z, b.w};
    #pragma unroll
    for (int j = 0; j < 8; ++j) {
        const unsigned short hi = f2bf(x[j]);
        h[j] = hi;
        l[j] = f2bf(x[j] - bf2f(hi));
    }
}

// async 16B global -> LDS
__device__ __forceinline__ void gload16(const void* g, void* l) {
    __builtin_amdgcn_global_load_lds(
        (const __attribute__((address_space(1))) void*)g,
        (__attribute__((address_space(3))) void*)l, 16, 0, 0);
}

// ---------------------------------------------------------------------------
// K0a: elementwise split of Q and V into bf16 hi/lo arrays ([n][row][h]).
// ---------------------------------------------------------------------------
__global__ __launch_bounds__(256) void k0_split(
    const float* __restrict__ Q, const float* __restrict__ V,
    unsigned short* __restrict__ Qh, unsigned short* __restrict__ Ql,
    unsigned short* __restrict__ Vh, unsigned short* __restrict__ Vl)
{
    const size_t i = ((size_t)blockIdx.x * 256 + threadIdx.x) * 8;
    const float* src = blockIdx.y ? V : Q;
    unsigned short* dh = blockIdx.y ? Vh : Qh;
    unsigned short* dl = blockIdx.y ? Vl : Ql;
    const float4 a = *(const float4*)&src[i];
    const float4 b = *(const float4*)&src[i + 4];
    ushort8v h, l;
    split8(a, b, h, l);
    *(ushort8v*)&dh[i] = h;
    *(ushort8v*)&dl[i] = l;
}

// ---------------------------------------------------------------------------
// K0b: VTf = bf16(V^T) in PRE-FRAGMENTED MFMA B-operand order:
//   VTf[n][k32][fn][lane][j] = bf16( V[n][k32*32 + (lane>>4)*8 + j][fn*16 + (lane&15)] )
// so k3's B loads are contiguous 1KB wave-loads (perfect coalescing).
// ---------------------------------------------------------------------------
__global__ __launch_bounds__(256) void k0_vt(
    const float* __restrict__ V, unsigned short* __restrict__ VTf)
{
    __shared__ unsigned short tile[64][68];      // [h-local][ti-local]
    const int n  = blockIdx.z;
    const int s0 = blockIdx.x * 64;              // ti base
    const int h0 = blockIdx.y * 64;              // h base
    const int t  = threadIdx.x;

    #pragma unroll
    for (int it = 0; it < 4; ++it) {             // read 64 ti x 64 h coalesced
        const int f = t + it * 256;
        const int r = f >> 4;                    // ti-local
        const int c = f & 15;                    // float4 group over h
        const float4 v = *(const float4*)&V[((size_t)(n * TIV + s0 + r)) * HD + h0 + 4 * c];
        tile[4 * c + 0][r] = f2bf(v.x);
        tile[4 * c + 1][r] = f2bf(v.y);
        tile[4 * c + 2][r] = f2bf(v.z);
        tile[4 * c + 3][r] = f2bf(v.w);
    }
    __syncthreads();

    // 512 slots of 16B (2 k32 x 4 fn x 64 lanes); thread t -> slots 2t, 2t+1.
    // Slot-linear == address-linear -> coalesced stores.
    #pragma unroll
    for (int it = 0; it < 2; ++it) {
        const int s    = t * 2 + it;
        const int k32i = s >> 8;                 // 0..1
        const int fni  = (s >> 6) & 3;           // 0..3
        const int l    = s & 63;                 // lane slot
        const int hh   = fni * 16 + (l & 15);
        const int kloc = k32i * 32 + ((l >> 4) * 8);
        ushort8v o;
        #pragma unroll
        for (int j = 0; j < 8; ++j) o[j] = tile[hh][kloc + j];
        const size_t k32g = (size_t)(s0 >> 5) + k32i;
        const size_t fng  = (size_t)(h0 >> 4) + fni;
        *(ushort8v*)&VTf[(((size_t)n * 64 + k32g) * 8 + fng) * 512 + (size_t)l * 8] = o;
    }
}

// ---------------------------------------------------------------------------
// K1 (fast): transposed QK^T (A=V, B=Q), global_load_lds staging of pre-split
// bf16 arrays, f32 E (16B stores — 8B/2B stores measured 1.6-3x slower here).
// ---------------------------------------------------------------------------
__global__ __launch_bounds__(256) void k1_lds(
    const unsigned short* __restrict__ QhG, const unsigned short* __restrict__ QlG,
    const unsigned short* __restrict__ VhG, const unsigned short* __restrict__ VlG,
    const int* __restrict__ M, float* __restrict__ E,
    float* __restrict__ part)
{
    __shared__ unsigned short qh_l[128 * 32], ql_l[128 * 32];
    __shared__ unsigned short vh_l[128 * 32], vl_l[128 * 32];

    const int n    = blockIdx.z;
    const int tt   = blockIdx.y * 128;
    const int ts   = blockIdx.x * 128;
    const int t    = threadIdx.x;
    const int lane = t & 63;
    const int wave = t >> 6;
    const int wr   = wave >> 1;
    const int wc   = wave & 1;
    const int lr   = lane & 15;
    const int kg   = lane >> 4;

    f32x4 acc[4][4];
    #pragma unroll
    for (int i = 0; i < 4; ++i)
        #pragma unroll
        for (int j = 0; j < 4; ++j) acc[i][j] = (f32x4)0.f;

    for (int h0 = 0; h0 < HD; h0 += 32) {
        #pragma unroll
        for (int j = 0; j < 2; ++j) {
            const int c    = wave * 128 + j * 64 + lane;
            const int row  = c >> 2;
            const int kb   = (c & 3) * 8;
            const int lb   = (wave * 128 + j * 64) * 8;
            const size_t qo = ((size_t)(n * TOQ + tt + row)) * HD + h0 + kb;
            const size_t vo = ((size_t)(n * TIV + ts + row)) * HD + h0 + kb;
            gload16(QhG + qo, qh_l + lb);
            gload16(QlG + qo, ql_l + lb);
            gload16(VhG + vo, vh_l + lb);
            gload16(VlG + vo, vl_l + lb);
        }
        __syncthreads();

        s16x8 aH[4], aL[4];
        #pragma unroll
        for (int fm = 0; fm < 4; ++fm) {
            const int off = (wr * 64 + fm * 16 + lr) * 32 + kg * 8;
            aH[fm] = *(const s16x8*)(vh_l + off);
            aL[fm] = *(const s16x8*)(vl_l + off);
        }
        #pragma unroll
        for (int fn = 0; fn < 4; ++fn) {
            const int off = (wc * 64 + fn * 16 + lr) * 32 + kg * 8;
            const s16x8 bH = *(const s16x8*)(qh_l + off);
            const s16x8 bL = *(const s16x8*)(ql_l + off);
            #pragma unroll
            for (int fm = 0; fm < 4; ++fm) {
                acc[fm][fn] = __builtin_amdgcn_mfma_f32_16x16x32_bf16(aH[fm], bH, acc[fm][fn], 0, 0, 0);
                acc[fm][fn] = __builtin_amdgcn_mfma_f32_16x16x32_bf16(aH[fm], bL, acc[fm][fn], 0, 0, 0);
                acc[fm][fn] = __builtin_amdgcn_mfma_f32_16x16x32_bf16(aL[fm], bH, acc[fm][fn], 0, 0, 0);
            }
        }
        __syncthreads();
    }

    #pragma unroll
    for (int fn = 0; fn < 4; ++fn) {
        const int to_g = tt + wc * 64 + fn * 16 + lr;
        const size_t rowbase = ((size_t)n * TOQ + to_g) * TIV;
        float rs = 0.f;
        #pragma unroll
        for (int fm = 0; fm < 4; ++fm) {
            const int ti_g = ts + wr * 64 + fm * 16 + kg * 4;
            const int4 mv = *(const int4*)&M[rowbase + ti_g];
            float4 e;
            e.x = mv.x ? 0.f : __expf(acc[fm][fn][0]);
            e.y = mv.y ? 0.f : __expf(acc[fm][fn][1]);
            e.z = mv.z ? 0.f : __expf(acc[fm][fn][2]);
            e.w = mv.w ? 0.f : __expf(acc[fm][fn][3]);
            *(float4*)&E[rowbase + ti_g] = e;
            rs += (e.x + e.y) + (e.z + e.w);
        }
        rs += __shfl_xor(rs, 16, 64);
        rs += __shfl_xor(rs, 32, 64);
        if (kg == 0)
            part[((size_t)n * TOQ + to_g) * 32 + blockIdx.x * 2 + wr] = rs;
    }
}

// ---------------------------------------------------------------------------
// K1 fallback (register-staged split) — used only if ws can't hold splits.
// ---------------------------------------------------------------------------
__global__ __launch_bounds__(256) void k1_reg(
    const float* __restrict__ Q, const float* __restrict__ V,
    const int* __restrict__ M, float* __restrict__ E,
    float* __restrict__ part)
{
    __shared__ unsigned short qhi[128 * 32], qlo[128 * 32];
    __shared__ unsigned short vhi[128 * 32], vlo[128 * 32];

    const int n    = blockIdx.z;
    const int tt   = blockIdx.y * 128;
    const int ts   = blockIdx.x * 128;
    const int t    = threadIdx.x;
    const int lane = t & 63;
    const int wave = t >> 6;
    const int wr   = wave >> 1;
    const int wc   = wave & 1;
    const int lr   = lane & 15;
    const int kg   = lane >> 4;

    const float* Qb = Q + ((size_t)n * TOQ + tt) * HD;
    const float* Vb = V + ((size_t)n * TIV + ts) * HD;

    f32x4 acc[4][4];
    #pragma unroll
    for (int i = 0; i < 4; ++i)
        #pragma unroll
        for (int j = 0; j < 4; ++j) acc[i][j] = (f32x4)0.f;

    for (int h0 = 0; h0 < HD; h0 += 32) {
        #pragma unroll
        for (int it = 0; it < 2; ++it) {
            const int i   = t + it * 256;
            const int row = i >> 2;
            const int kb  = i & 3;
            const float* qs = Qb + (size_t)row * HD + h0 + kb * 8;
            const float* vs = Vb + (size_t)row * HD + h0 + kb * 8;
            const float4 q0 = *(const float4*)qs, q1 = *(const float4*)(qs + 4);
            const float4 v0 = *(const float4*)vs, v1 = *(const float4*)(vs + 4);
            ushort8v qh, ql, vh, vl;
            split8(q0, q1, qh, ql);
            split8(v0, v1, vh, vl);
            *(ushort8v*)(qhi + i * 8) = qh;
            *(ushort8v*)(qlo + i * 8) = ql;
            *(ushort8v*)(vhi + i * 8) = vh;
            *(ushort8v*)(vlo + i * 8) = vl;
        }
        __syncthreads();

        s16x8 aH[4], aL[4];
        #pragma unroll
        for (int fm = 0; fm < 4; ++fm) {
            const int off = (wr * 64 + fm * 16 + lr) * 32 + kg * 8;
            aH[fm] = *(const s16x8*)(vhi + off);
            aL[fm] = *(const s16x8*)(vlo + off);
        }
        #pragma unroll
        for (int fn = 0; fn < 4; ++fn) {
            const int off = (wc * 64 + fn * 16 + lr) * 32 + kg * 8;
            const s16x8 bH = *(const s16x8*)(qhi + off);
            const s16x8 bL = *(const s16x8*)(qlo + off);
            #pragma unroll
            for (int fm = 0; fm < 4; ++fm) {
                acc[fm][fn] = __builtin_amdgcn_mfma_f32_16x16x32_bf16(aH[fm], bH, acc[fm][fn], 0, 0, 0);
                acc[fm][fn] = __builtin_amdgcn_mfma_f32_16x16x32_bf16(aH[fm], bL, acc[fm][fn], 0, 0, 0);
                acc[fm][fn] = __builtin_amdgcn_mfma_f32_16x16x32_bf16(aL[fm], bH, acc[fm][fn], 0, 0, 0);
            }
        }
        __syncthreads();
    }

    #pragma unroll
    for (int fn = 0; fn < 4; ++fn) {
        const int to_g = tt + wc * 64 + fn * 16 + lr;
        const size_t rowbase = ((size_t)n * TOQ + to_g) * TIV;
        float rs = 0.f;
        #pragma unroll
        for (int fm = 0; fm < 4; ++fm) {
            const int ti_g = ts + wr * 64 + fm * 16 + kg * 4;
            const int4 mv = *(const int4*)&M[rowbase + ti_g];
            float4 e;
            e.x = mv.x ? 0.f : __expf(acc[fm][fn][0]);
            e.y = mv.y ? 0.f : __expf(acc[fm][fn][1]);
            e.z = mv.z ? 0.f : __expf(acc[fm][fn][2]);
            e.w = mv.w ? 0.f : __expf(acc[fm][fn][3]);
            *(float4*)&E[rowbase + ti_g] = e;
            rs += (e.x + e.y) + (e.z + e.w);
        }
        rs += __shfl_xor(rs, 16, 64);
        rs += __shfl_xor(rs, 32, 64);
        if (kg == 0)
            part[((size_t)n * TOQ + to_g) * 32 + blockIdx.x * 2 + wr] = rs;
    }
}

// ---------------------------------------------------------------------------
// K2: rec[row] = 1 / sum of 32 partials
// ---------------------------------------------------------------------------
__global__ __launch_bounds__(256) void k2_rowsum(
    const float* __restrict__ part, float* __restrict__ rec)
{
    const int row = blockIdx.x * 256 + threadIdx.x;
    const float4* p4 = (const float4*)(part + (size_t)row * 32);
    float s = 0.f;
    #pragma unroll
    for (int i = 0; i < 8; ++i) {
        const float4 v = p4[i];
        s += (v.x + v.y) + (v.z + v.w);
    }
    rec[row] = 1.f / s;
}

// ---------------------------------------------------------------------------
// K3: fused normalize + P-writeback + MFMA PV — fully COALESCED version.
//  - E loads & P stores: row-major, 4 rows x 512B contiguous per instr
//  - A-fragments: per-wave LDS staging (ds_write -> ds_read, same wave, no
//    cross-wave barrier in the main loop)
//  - B-fragments: contiguous 1KB wave-loads from pre-fragmented VTf
//  - epilogue: 4-wave reduction via LDS (unioned with staging buffer)
// ---------------------------------------------------------------------------
__global__ __launch_bounds__(512) void k3_pv(
    float* __restrict__ EP, const unsigned short* __restrict__ VTf,
    const float* __restrict__ rec, float* __restrict__ O)
{
    __shared__ __attribute__((aligned(16))) char smem[50688];
    unsigned short* stg = (unsigned short*)smem;   // [8 waves][16 rows][136]
    float*          red = (float*)smem;            // [2][3][16][132]

    const int n    = blockIdx.y;
    const int r0   = blockIdx.x * 32;
    const int t    = threadIdx.x;
    const int wave = t >> 6;
    const int lane = t & 63;
    const int p    = wave >> 2;                    // row group (16 rows)
    const int q    = wave & 3;                     // k quarter (512 ti)
    const int lr   = lane & 15;
    const int kg   = lane >> 4;

    const size_t rowbase0 = (size_t)n * TOQ + r0 + p * 16;
    unsigned short* wstg = stg + wave * (16 * 136);

    // preload rec for the 4 rows this lane stages (round r -> row 4r+kg)
    float rv[4];
    #pragma unroll
    for (int r = 0; r < 4; ++r) rv[r] = rec[rowbase0 + 4 * r + kg];

    f32x4 acc[8];
    #pragma unroll
    for (int fn = 0; fn < 8; ++fn) acc[fn] = (f32x4)0.f;

    const unsigned short* VTn = VTf + (size_t)n * 64 * 8 * 512;

    for (int kb = 0; kb < 4; ++kb) {
        const int kwin = q * 512 + kb * 128;

        // stage: 4 rounds x 4 rows; 512B contiguous per row (coalesced)
        #pragma unroll
        for (int r = 0; r < 4; ++r) {
            const int row_l = 4 * r + kg;
            float* Erow = EP + (rowbase0 + row_l) * TIV + kwin + lr * 8;
            const float4 e0 = *(const float4*)Erow;
            const float4 e1 = *(const float4*)(Erow + 4);
            const float rc = rv[r];
            float4 p0, p1;
            p0.x = e0.x * rc; p0.y = e0.y * rc; p0.z = e0.z * rc; p0.w = e0.w * rc;
            p1.x = e1.x * rc; p1.y = e1.y * rc; p1.z = e1.z * rc; p1.w = e1.w * rc;
            *(float4*)Erow       = p0;             // P output (coalesced)
            *(float4*)(Erow + 4) = p1;
            ushort8v s8;
            s8[0] = f2bf(p0.x); s8[1] = f2bf(p0.y); s8[2] = f2bf(p0.z); s8[3] = f2bf(p0.w);
            s8[4] = f2bf(p1.x); s8[5] = f2bf(p1.y); s8[6] = f2bf(p1.z); s8[7] = f2bf(p1.w);
            *(ushort8v*)&wstg[row_l * 136 + lr * 8] = s8;
        }

        // compute: 4 k-steps of 32; A from own LDS slice, B coalesced from VTf
        #pragma unroll
        for (int ks = 0; ks < 4; ++ks) {
            const s16x8 a = *(const s16x8*)&wstg[lr * 136 + ks * 32 + kg * 8];
            const int k32 = q * 16 + kb * 4 + ks;
            const unsigned short* bbase = VTn + ((size_t)k32 * 8) * 512 + (size_t)lane * 8;
            #pragma unroll
            for (int fn = 0; fn < 8; ++fn) {
                const s16x8 b = *(const s16x8*)(bbase + (size_t)fn * 512);
                acc[fn] = __builtin_amdgcn_mfma_f32_16x16x32_bf16(a, b, acc[fn], 0, 0, 0);
            }
        }
    }

    // epilogue: all waves done with stg before red overwrites it
    __syncthreads();
    if (q != 0) {
        #pragma unroll
        for (int fn = 0; fn < 8; ++fn)
            #pragma unroll
            for (int ri = 0; ri < 4; ++ri)
                red[(((size_t)p * 3 + (q - 1)) * 16 + kg * 4 + ri) * 132 + fn * 16 + lr] = acc[fn][ri];
    }
    __syncthreads();
    if (q == 0) {
        #pragma unroll
        for (int fn = 0; fn < 8; ++fn) {
            #pragma unroll
            for (int ri = 0; ri < 4; ++ri) {
                const int orow = r0 + p * 16 + kg * 4 + ri;
                float o = acc[fn][ri];
                o += red[(((size_t)p * 3 + 0) * 16 + kg * 4 + ri) * 132 + fn * 16 + lr];
                o += red[(((size_t)p * 3 + 1) * 16 + kg * 4 + ri) * 132 + fn * 16 + lr];
                o += red[(((size_t)p * 3 + 2) * 16 + kg * 4 + ri) * 132 + fn * 16 + lr];
                O[((size_t)n * TOQ + orow) * HD + fn * 16 + lr] = o;
            }
        }
    }
}

// ---------------------------------------------------------------------------
extern "C" void kernel_launch(void* const* d_in, const int* in_sizes, int n_in,
                              void* d_out, int out_size, void* d_ws, size_t ws_size,
                              hipStream_t stream)
{
    const float* Q = (const float*)d_in[0];
    const float* V = (const float*)d_in[1];
    const int*   M = (const int*)d_in[2];

    float* O = (float*)d_out;                         // [8][2048][128] f32
    float* P = O + (size_t)NB * TOQ * HD;             // [8][2048][2048] f32 (E then P)

    char* ws = (char*)d_ws;
    const size_t partB  = (size_t)NB * TOQ * 32 * 4;  // 2 MB
    const size_t vtB    = (size_t)NB * 64 * 8 * 512 * 2; // 4 MB (VTf)
    const size_t elems  = (size_t)NB * TOQ * HD;
    const size_t sbytes = elems * 2;                  // 4 MB per split array

    float*          recb = (float*)ws;
    float*          part = (float*)(ws + (1 << 16));
    unsigned short* VTf  = (unsigned short*)(ws + (1 << 16) + partB);
    const size_t splitOff = (1 << 16) + partB + vtB;
    const size_t need1    = splitOff + 4 * sbytes;    // ~22.1 MB

    k0_vt<<<dim3(TIV / 64, HD / 64, NB), 256, 0, stream>>>(V, VTf);

    if (ws_size >= need1) {
        unsigned short* Qh = (unsigned short*)(ws + splitOff);
        unsigned short* Ql = (unsigned short*)(ws + splitOff + sbytes);
        unsigned short* Vh = (unsigned short*)(ws + splitOff + 2 * sbytes);
        unsigned short* Vl = (unsigned short*)(ws + splitOff + 3 * sbytes);
        k0_split<<<dim3((unsigned)(elems / 8 / 256), 2), 256, 0, stream>>>(Q, V, Qh, Ql, Vh, Vl);
        k1_lds  <<<dim3(TIV / 128, TOQ / 128, NB), 256, 0, stream>>>(Qh, Ql, Vh, Vl, M, P, part);
    } else {
        k1_reg  <<<dim3(TIV / 128, TOQ / 128, NB), 256, 0, stream>>>(Q, V, M, P, part);
    }

    k2_rowsum<<<dim3(NB * TOQ / 256), 256, 0, stream>>>(part, recb);
    k3_pv    <<<dim3(TOQ / 32, NB), 512, 0, stream>>>(P, VTf, recb, O);
}

// Round 14
// 181.765 us; speedup vs baseline: 1.0071x; 1.0071x over previous
//
#include <hip/hip_runtime.h>

#define NB  8
#define TOQ 2048
#define TIV 2048
#define HD  128

typedef float f32x4 __attribute__((ext_vector_type(4)));
typedef short s16x8 __attribute__((ext_vector_type(8)));
typedef unsigned short ushort4v __attribute__((ext_vector_type(4)));
typedef unsigned short ushort8v __attribute__((ext_vector_type(8)));

__device__ __forceinline__ unsigned short f2bf(float f) {   // RNE f32->bf16
    unsigned u = __float_as_uint(f);
    return (unsigned short)((u + 0x7FFFu + ((u >> 16) & 1u)) >> 16);
}
__device__ __forceinline__ float bf2f(unsigned short h) {
    return __uint_as_float(((unsigned)h) << 16);
}

__device__ __forceinline__ void split8(const float4 a, const float4 b,
                                       ushort8v& h, ushort8v& l) {
    const float x[8] = {a.x, a.y, a.z, a.w, b.x, b.y, b.z, b.w};
    #pragma unroll
    for (int j = 0; j < 8; ++j) {
        const unsigned short hi = f2bf(x[j]);
        h[j] = hi;
        l[j] = f2bf(x[j] - bf2f(hi));
    }
}

// async 16B global -> LDS (wave-uniform LDS base + lane*16)
__device__ __forceinline__ void gload16(const void* g, void* l) {
    __builtin_amdgcn_global_load_lds(
        (const __attribute__((address_space(1))) void*)g,
        (__attribute__((address_space(3))) void*)l, 16, 0, 0);
}

// ---------------------------------------------------------------------------
// K0a: elementwise split of Q and V into bf16 hi/lo arrays ([n][row][h]).
// ---------------------------------------------------------------------------
__global__ __launch_bounds__(256) void k0_split(
    const float* __restrict__ Q, const float* __restrict__ V,
    unsigned short* __restrict__ Qh, unsigned short* __restrict__ Ql,
    unsigned short* __restrict__ Vh, unsigned short* __restrict__ Vl)
{
    const size_t i = ((size_t)blockIdx.x * 256 + threadIdx.x) * 8;
    const float* src = blockIdx.y ? V : Q;
    unsigned short* dh = blockIdx.y ? Vh : Qh;
    unsigned short* dl = blockIdx.y ? Vl : Ql;
    const float4 a = *(const float4*)&src[i];
    const float4 b = *(const float4*)&src[i + 4];
    ushort8v h, l;
    split8(a, b, h, l);
    *(ushort8v*)&dh[i] = h;
    *(ushort8v*)&dl[i] = l;
}

// ---------------------------------------------------------------------------
// K0b: VTf = bf16(V^T) pre-fragmented in MFMA B-operand order (r13, verified):
//   VTf[n][k32][fn][lane][j] = bf16(V[n][k32*32+(lane>>4)*8+j][fn*16+(lane&15)])
// ---------------------------------------------------------------------------
__global__ __launch_bounds__(256) void k0_vtf(
    const float* __restrict__ V, unsigned short* __restrict__ VTf)
{
    __shared__ unsigned short tile[64][68];
    const int n  = blockIdx.z;
    const int s0 = blockIdx.x * 64;
    const int h0 = blockIdx.y * 64;
    const int t  = threadIdx.x;

    #pragma unroll
    for (int it = 0; it < 4; ++it) {
        const int f = t + it * 256;
        const int r = f >> 4;
        const int c = f & 15;
        const float4 v = *(const float4*)&V[((size_t)(n * TIV + s0 + r)) * HD + h0 + 4 * c];
        tile[4 * c + 0][r] = f2bf(v.x);
        tile[4 * c + 1][r] = f2bf(v.y);
        tile[4 * c + 2][r] = f2bf(v.z);
        tile[4 * c + 3][r] = f2bf(v.w);
    }
    __syncthreads();

    #pragma unroll
    for (int it = 0; it < 2; ++it) {
        const int s    = t * 2 + it;
        const int k32i = s >> 8;
        const int fni  = (s >> 6) & 3;
        const int l    = s & 63;
        const int hh   = fni * 16 + (l & 15);
        const int kloc = k32i * 32 + ((l >> 4) * 8);
        ushort8v o;
        #pragma unroll
        for (int j = 0; j < 8; ++j) o[j] = tile[hh][kloc + j];
        const size_t k32g = (size_t)(s0 >> 5) + k32i;
        const size_t fng  = (size_t)(h0 >> 4) + fni;
        *(ushort8v*)&VTf[(((size_t)n * 64 + k32g) * 8 + fng) * 512 + (size_t)l * 8] = o;
    }
}

// ---------------------------------------------------------------------------
// K0b' (fallback): VT[n][h][s] layout for the fallback k3.
// ---------------------------------------------------------------------------
__global__ __launch_bounds__(256) void k0_vt_old(
    const float* __restrict__ V, unsigned short* __restrict__ VT)
{
    __shared__ unsigned short tile[64][68];
    const int n  = blockIdx.z;
    const int s0 = blockIdx.x * 64;
    const int h0 = blockIdx.y * 64;
    const int t  = threadIdx.x;

    #pragma unroll
    for (int it = 0; it < 4; ++it) {
        const int f = t + it * 256;
        const int r = f >> 4;
        const int c = f & 15;
        const float4 v = *(const float4*)&V[((size_t)(n * TIV + s0 + r)) * HD + h0 + 4 * c];
        tile[4 * c + 0][r] = f2bf(v.x);
        tile[4 * c + 1][r] = f2bf(v.y);
        tile[4 * c + 2][r] = f2bf(v.z);
        tile[4 * c + 3][r] = f2bf(v.w);
    }
    __syncthreads();

    #pragma unroll
    for (int it = 0; it < 2; ++it) {
        const int f  = t + it * 256;
        const int hh = f >> 3;
        const int sc = f & 7;
        ushort8v o;
        #pragma unroll
        for (int j = 0; j < 8; ++j) o[j] = tile[hh][8 * sc + j];
        *(ushort8v*)&VT[((size_t)(n * HD + h0 + hh)) * TIV + s0 + 8 * sc] = o;
    }
}

// ---------------------------------------------------------------------------
// K1 (tier2): 8-wave / 512-thread transposed QK^T (A=V,B=Q).
// Wave (wr 0..1, wc 0..3) owns a 64(ti) x 32(to) sub-tile: acc[4][2] = 32 AGPR
// (half the old 64) -> higher occupancy. global_load_lds staging of pre-split
// bf16 hi/lo arrays; bf16 E out (ushort4 stores); fused 2-shfl row partials.
// ---------------------------------------------------------------------------
__global__ __launch_bounds__(512) void k1_w8(
    const unsigned short* __restrict__ QhG, const unsigned short* __restrict__ QlG,
    const unsigned short* __restrict__ VhG, const unsigned short* __restrict__ VlG,
    const int* __restrict__ M, unsigned short* __restrict__ Eb,
    float* __restrict__ part)
{
    __shared__ unsigned short qh_l[128 * 32], ql_l[128 * 32];
    __shared__ unsigned short vh_l[128 * 32], vl_l[128 * 32];

    const int n    = blockIdx.z;
    const int tt   = blockIdx.y * 128;   // to-rows (Q side)
    const int ts   = blockIdx.x * 128;   // ti-cols (V side)
    const int t    = threadIdx.x;
    const int lane = t & 63;
    const int wave = t >> 6;             // 0..7
    const int wr   = wave >> 2;          // ti half   (0..1)
    const int wc   = wave & 3;           // to quarter (0..3)
    const int lr   = lane & 15;
    const int kg   = lane >> 4;

    f32x4 acc[4][2];                     // [fm: ti][fn: to]
    #pragma unroll
    for (int i = 0; i < 4; ++i)
        #pragma unroll
        for (int j = 0; j < 2; ++j) acc[i][j] = (f32x4)0.f;

    for (int h0 = 0; h0 < HD; h0 += 32) {
        // stage: 512 chunks of 16B per array; thread t -> chunk t
        {
            const int c   = wave * 64 + lane;
            const int row = c >> 2;
            const int kb  = (c & 3) * 8;
            const int lb  = wave * 512;          // ushort base (wave-uniform)
            const size_t qo = ((size_t)(n * TOQ + tt + row)) * HD + h0 + kb;
            const size_t vo = ((size_t)(n * TIV + ts + row)) * HD + h0 + kb;
            gload16(QhG + qo, qh_l + lb);
            gload16(QlG + qo, ql_l + lb);
            gload16(VhG + vo, vh_l + lb);
            gload16(VlG + vo, vl_l + lb);
        }
        __syncthreads();

        s16x8 aH[4], aL[4];
        #pragma unroll
        for (int fm = 0; fm < 4; ++fm) {
            const int off = (wr * 64 + fm * 16 + lr) * 32 + kg * 8;
            aH[fm] = *(const s16x8*)(vh_l + off);
            aL[fm] = *(const s16x8*)(vl_l + off);
        }
        #pragma unroll
        for (int fn = 0; fn < 2; ++fn) {
            const int off = (wc * 32 + fn * 16 + lr) * 32 + kg * 8;
            const s16x8 bH = *(const s16x8*)(qh_l + off);
            const s16x8 bL = *(const s16x8*)(ql_l + off);
            #pragma unroll
            for (int fm = 0; fm < 4; ++fm) {
                acc[fm][fn] = __builtin_amdgcn_mfma_f32_16x16x32_bf16(aH[fm], bH, acc[fm][fn], 0, 0, 0);
                acc[fm][fn] = __builtin_amdgcn_mfma_f32_16x16x32_bf16(aH[fm], bL, acc[fm][fn], 0, 0, 0);
                acc[fm][fn] = __builtin_amdgcn_mfma_f32_16x16x32_bf16(aL[fm], bH, acc[fm][fn], 0, 0, 0);
            }
        }
        __syncthreads();
    }

    // epilogue: lane owns 4 consecutive ti per (fm,fn); int4 mask, 8B E store
    #pragma unroll
    for (int fn = 0; fn < 2; ++fn) {
        const int to_g = tt + wc * 32 + fn * 16 + lr;
        const size_t rowbase = ((size_t)n * TOQ + to_g) * TIV;
        float rs = 0.f;
        #pragma unroll
        for (int fm = 0; fm < 4; ++fm) {
            const int ti_g = ts + wr * 64 + fm * 16 + kg * 4;
            const int4 mv = *(const int4*)&M[rowbase + ti_g];
            float4 e;
            e.x = mv.x ? 0.f : __expf(acc[fm][fn][0]);
            e.y = mv.y ? 0.f : __expf(acc[fm][fn][1]);
            e.z = mv.z ? 0.f : __expf(acc[fm][fn][2]);
            e.w = mv.w ? 0.f : __expf(acc[fm][fn][3]);
            ushort4v eb;
            eb[0] = f2bf(e.x); eb[1] = f2bf(e.y);
            eb[2] = f2bf(e.z); eb[3] = f2bf(e.w);
            *(ushort4v*)&Eb[rowbase + ti_g] = eb;
            rs += (e.x + e.y) + (e.z + e.w);
        }
        rs += __shfl_xor(rs, 16, 64);
        rs += __shfl_xor(rs, 32, 64);
        if (kg == 0)
            part[((size_t)n * TOQ + to_g) * 32 + blockIdx.x * 2 + wr] = rs;
    }
}

// ---------------------------------------------------------------------------
// K1 fallback (r10 verbatim): register-staged split, f32 E, 4 waves.
// ---------------------------------------------------------------------------
__global__ __launch_bounds__(256) void k1_reg(
    const float* __restrict__ Q, const float* __restrict__ V,
    const int* __restrict__ M, float* __restrict__ E,
    float* __restrict__ part)
{
    __shared__ unsigned short qhi[128 * 32], qlo[128 * 32];
    __shared__ unsigned short vhi[128 * 32], vlo[128 * 32];

    const int n    = blockIdx.z;
    const int tt   = blockIdx.y * 128;
    const int ts   = blockIdx.x * 128;
    const int t    = threadIdx.x;
    const int lane = t & 63;
    const int wave = t >> 6;
    const int wr   = wave >> 1;
    const int wc   = wave & 1;
    const int lr   = lane & 15;
    const int kg   = lane >> 4;

    const float* Qb = Q + ((size_t)n * TOQ + tt) * HD;
    const float* Vb = V + ((size_t)n * TIV + ts) * HD;

    f32x4 acc[4][4];
    #pragma unroll
    for (int i = 0; i < 4; ++i)
        #pragma unroll
        for (int j = 0; j < 4; ++j) acc[i][j] = (f32x4)0.f;

    for (int h0 = 0; h0 < HD; h0 += 32) {
        #pragma unroll
        for (int it = 0; it < 2; ++it) {
            const int i   = t + it * 256;
            const int row = i >> 2;
            const int kb  = i & 3;
            const float* qs = Qb + (size_t)row * HD + h0 + kb * 8;
            const float* vs = Vb + (size_t)row * HD + h0 + kb * 8;
            const float4 q0 = *(const float4*)qs, q1 = *(const float4*)(qs + 4);
            const float4 v0 = *(const float4*)vs, v1 = *(const float4*)(vs + 4);
            ushort8v qh, ql, vh, vl;
            split8(q0, q1, qh, ql);
            split8(v0, v1, vh, vl);
            *(ushort8v*)(qhi + i * 8) = qh;
            *(ushort8v*)(qlo + i * 8) = ql;
            *(ushort8v*)(vhi + i * 8) = vh;
            *(ushort8v*)(vlo + i * 8) = vl;
        }
        __syncthreads();

        s16x8 aH[4], aL[4];
        #pragma unroll
        for (int fm = 0; fm < 4; ++fm) {
            const int off = (wr * 64 + fm * 16 + lr) * 32 + kg * 8;
            aH[fm] = *(const s16x8*)(vhi + off);
            aL[fm] = *(const s16x8*)(vlo + off);
        }
        #pragma unroll
        for (int fn = 0; fn < 4; ++fn) {
            const int off = (wc * 64 + fn * 16 + lr) * 32 + kg * 8;
            const s16x8 bH = *(const s16x8*)(qhi + off);
            const s16x8 bL = *(const s16x8*)(qlo + off);
            #pragma unroll
            for (int fm = 0; fm < 4; ++fm) {
                acc[fm][fn] = __builtin_amdgcn_mfma_f32_16x16x32_bf16(aH[fm], bH, acc[fm][fn], 0, 0, 0);
                acc[fm][fn] = __builtin_amdgcn_mfma_f32_16x16x32_bf16(aH[fm], bL, acc[fm][fn], 0, 0, 0);
                acc[fm][fn] = __builtin_amdgcn_mfma_f32_16x16x32_bf16(aL[fm], bH, acc[fm][fn], 0, 0, 0);
            }
        }
        __syncthreads();
    }

    #pragma unroll
    for (int fn = 0; fn < 4; ++fn) {
        const int to_g = tt + wc * 64 + fn * 16 + lr;
        const size_t rowbase = ((size_t)n * TOQ + to_g) * TIV;
        float rs = 0.f;
        #pragma unroll
        for (int fm = 0; fm < 4; ++fm) {
            const int ti_g = ts + wr * 64 + fm * 16 + kg * 4;
            const int4 mv = *(const int4*)&M[rowbase + ti_g];
            float4 e;
            e.x = mv.x ? 0.f : __expf(acc[fm][fn][0]);
            e.y = mv.y ? 0.f : __expf(acc[fm][fn][1]);
            e.z = mv.z ? 0.f : __expf(acc[fm][fn][2]);
            e.w = mv.w ? 0.f : __expf(acc[fm][fn][3]);
            *(float4*)&E[rowbase + ti_g] = e;
            rs += (e.x + e.y) + (e.z + e.w);
        }
        rs += __shfl_xor(rs, 16, 64);
        rs += __shfl_xor(rs, 32, 64);
        if (kg == 0)
            part[((size_t)n * TOQ + to_g) * 32 + blockIdx.x * 2 + wr] = rs;
    }
}

// ---------------------------------------------------------------------------
// K2: rec[row] = 1 / sum of 32 partials
// ---------------------------------------------------------------------------
__global__ __launch_bounds__(256) void k2_rowsum(
    const float* __restrict__ part, float* __restrict__ rec)
{
    const int row = blockIdx.x * 256 + threadIdx.x;
    const float4* p4 = (const float4*)(part + (size_t)row * 32);
    float s = 0.f;
    #pragma unroll
    for (int i = 0; i < 8; ++i) {
        const float4 v = p4[i];
        s += (v.x + v.y) + (v.z + v.w);
    }
    rec[row] = 1.f / s;
}

// ---------------------------------------------------------------------------
// K3 (tier2): bf16 E (row-coalesced reads) + per-wave LDS A-staging + VTf
// coalesced B loads + REGISTER PREFETCH of next 128-col window (MLP x2).
// P written f32 to its own buffer (fire-and-forget); O via 4-wave reduction.
// ---------------------------------------------------------------------------
__global__ __launch_bounds__(512) void k3_pf(
    const unsigned short* __restrict__ Eb, const unsigned short* __restrict__ VTf,
    const float* __restrict__ rec, float* __restrict__ P, float* __restrict__ O)
{
    __shared__ __attribute__((aligned(16))) char smem[50688];
    unsigned short* stg = (unsigned short*)smem;   // [8 waves][16 rows][136]
    float*          red = (float*)smem;            // [2][3][16][132]

    const int n    = blockIdx.y;
    const int r0   = blockIdx.x * 32;
    const int t    = threadIdx.x;
    const int wave = t >> 6;
    const int lane = t & 63;
    const int p    = wave >> 2;                    // row group
    const int q    = wave & 3;                     // k quarter (512 cols)
    const int lr   = lane & 15;
    const int kg   = lane >> 4;

    const size_t rowbase0 = (size_t)n * TOQ + r0 + p * 16;
    unsigned short* wstg = stg + wave * (16 * 136);

    float rv[4];
    #pragma unroll
    for (int r = 0; r < 4; ++r) rv[r] = rec[rowbase0 + 4 * r + kg];

    f32x4 acc[8];
    #pragma unroll
    for (int fn = 0; fn < 8; ++fn) acc[fn] = (f32x4)0.f;

    const unsigned short* VTn = VTf + (size_t)n * 64 * 8 * 512;

    // prologue: load window kb=0 (per lane: rows 4r+kg, 16B of bf16 = 8 cols)
    ushort8v ev[4];
    #pragma unroll
    for (int r = 0; r < 4; ++r)
        ev[r] = *(const ushort8v*)&Eb[(rowbase0 + 4 * r + kg) * TIV + q * 512 + lr * 8];

    for (int kb = 0; kb < 4; ++kb) {
        const int kwin = q * 512 + kb * 128;

        // scale current window, store P (coalesced 512B/row), stage A to LDS
        #pragma unroll
        for (int r = 0; r < 4; ++r) {
            const int row_l = 4 * r + kg;
            float pv[8];
            #pragma unroll
            for (int j = 0; j < 8; ++j) pv[j] = bf2f(ev[r][j]) * rv[r];
            float4 p0, p1;
            p0.x = pv[0]; p0.y = pv[1]; p0.z = pv[2]; p0.w = pv[3];
            p1.x = pv[4]; p1.y = pv[5]; p1.z = pv[6]; p1.w = pv[7];
            float* Prow = P + (rowbase0 + row_l) * TIV + kwin + lr * 8;
            *(float4*)Prow       = p0;
            *(float4*)(Prow + 4) = p1;
            ushort8v s8;
            #pragma unroll
            for (int j = 0; j < 8; ++j) s8[j] = f2bf(pv[j]);
            *(ushort8v*)&wstg[row_l * 136 + lr * 8] = s8;
        }

        // prefetch next window into regs (in flight during MFMA below)
        if (kb < 3) {
            #pragma unroll
            for (int r = 0; r < 4; ++r)
                ev[r] = *(const ushort8v*)&Eb[(rowbase0 + 4 * r + kg) * TIV + kwin + 128 + lr * 8];
        }

        // compute: 4 k-steps of 32; A from own LDS slice, B coalesced from VTf
        #pragma unroll
        for (int ks = 0; ks < 4; ++ks) {
            const s16x8 a = *(const s16x8*)&wstg[lr * 136 + ks * 32 + kg * 8];
            const int k32 = q * 16 + kb * 4 + ks;
            const unsigned short* bbase = VTn + ((size_t)k32 * 8) * 512 + (size_t)lane * 8;
            #pragma unroll
            for (int fn = 0; fn < 8; ++fn) {
                const s16x8 b = *(const s16x8*)(bbase + (size_t)fn * 512);
                acc[fn] = __builtin_amdgcn_mfma_f32_16x16x32_bf16(a, b, acc[fn], 0, 0, 0);
            }
        }
    }

    __syncthreads();                               // stg -> red reuse
    if (q != 0) {
        #pragma unroll
        for (int fn = 0; fn < 8; ++fn)
            #pragma unroll
            for (int ri = 0; ri < 4; ++ri)
                red[(((size_t)p * 3 + (q - 1)) * 16 + kg * 4 + ri) * 132 + fn * 16 + lr] = acc[fn][ri];
    }
    __syncthreads();
    if (q == 0) {
        #pragma unroll
        for (int fn = 0; fn < 8; ++fn) {
            #pragma unroll
            for (int ri = 0; ri < 4; ++ri) {
                const int orow = r0 + p * 16 + kg * 4 + ri;
                float o = acc[fn][ri];
                o += red[(((size_t)p * 3 + 0) * 16 + kg * 4 + ri) * 132 + fn * 16 + lr];
                o += red[(((size_t)p * 3 + 1) * 16 + kg * 4 + ri) * 132 + fn * 16 + lr];
                o += red[(((size_t)p * 3 + 2) * 16 + kg * 4 + ri) * 132 + fn * 16 + lr];
                O[((size_t)n * TOQ + orow) * HD + fn * 16 + lr] = o;
            }
        }
    }
}

// ---------------------------------------------------------------------------
// K3 fallback (r11 verbatim): in-place f32 E->P, scattered VT.
// ---------------------------------------------------------------------------
__global__ __launch_bounds__(512) void k3_pv_old(
    float* __restrict__ EP, const unsigned short* __restrict__ VT,
    const float* __restrict__ rec, float* __restrict__ O)
{
    __shared__ float red[2][3][16][132];

    const int n    = blockIdx.y;
    const int r0   = blockIdx.x * 32;
    const int t    = threadIdx.x;
    const int wave = t >> 6;
    const int lane = t & 63;
    const int p    = wave >> 2;
    const int q    = wave & 3;
    const int lr   = lane & 15;
    const int kg   = lane >> 4;

    const int rowg = r0 + p * 16 + lr;
    const float rc = rec[n * TOQ + rowg];
    float* Erow = EP + ((size_t)n * TOQ + rowg) * TIV;
    const unsigned short* VTb = VT + (size_t)n * HD * TIV;

    f32x4 acc[8];
    #pragma unroll
    for (int fn = 0; fn < 8; ++fn) acc[fn] = (f32x4)0.f;

    const int kbase = q * 512 + kg * 8;

    #pragma unroll 2
    for (int k0 = 0; k0 < 512; k0 += 32) {
        const int k = kbase + k0;
        const float4 e0 = *(const float4*)&Erow[k];
        const float4 e1 = *(const float4*)&Erow[k + 4];
        float4 p0, p1;
        p0.x = e0.x * rc; p0.y = e0.y * rc; p0.z = e0.z * rc; p0.w = e0.w * rc;
        p1.x = e1.x * rc; p1.y = e1.y * rc; p1.z = e1.z * rc; p1.w = e1.w * rc;
        *(float4*)&Erow[k]     = p0;
        *(float4*)&Erow[k + 4] = p1;

        s16x8 a;
        a[0] = (short)f2bf(p0.x); a[1] = (short)f2bf(p0.y);
        a[2] = (short)f2bf(p0.z); a[3] = (short)f2bf(p0.w);
        a[4] = (short)f2bf(p1.x); a[5] = (short)f2bf(p1.y);
        a[6] = (short)f2bf(p1.z); a[7] = (short)f2bf(p1.w);

        #pragma unroll
        for (int fn = 0; fn < 8; ++fn) {
            const s16x8 b = *(const s16x8*)&VTb[(size_t)(fn * 16 + lr) * TIV + k];
            acc[fn] = __builtin_amdgcn_mfma_f32_16x16x32_bf16(a, b, acc[fn], 0, 0, 0);
        }
    }

    if (q != 0) {
        #pragma unroll
        for (int fn = 0; fn < 8; ++fn)
            #pragma unroll
            for (int ri = 0; ri < 4; ++ri)
                red[p][q - 1][kg * 4 + ri][fn * 16 + lr] = acc[fn][ri];
    }
    __syncthreads();
    if (q == 0) {
        #pragma unroll
        for (int fn = 0; fn < 8; ++fn) {
            #pragma unroll
            for (int ri = 0; ri < 4; ++ri) {
                const int orow = r0 + p * 16 + kg * 4 + ri;
                float o = acc[fn][ri];
                o += red[p][0][kg * 4 + ri][fn * 16 + lr];
                o += red[p][1][kg * 4 + ri][fn * 16 + lr];
                o += red[p][2][kg * 4 + ri][fn * 16 + lr];
                O[((size_t)n * TOQ + orow) * HD + fn * 16 + lr] = o;
            }
        }
    }
}

// ---------------------------------------------------------------------------
extern "C" void kernel_launch(void* const* d_in, const int* in_sizes, int n_in,
                              void* d_out, int out_size, void* d_ws, size_t ws_size,
                              hipStream_t stream)
{
    const float* Q = (const float*)d_in[0];
    const float* V = (const float*)d_in[1];
    const int*   M = (const int*)d_in[2];

    float* O = (float*)d_out;                         // [8][2048][128] f32
    float* P = O + (size_t)NB * TOQ * HD;             // [8][2048][2048] f32

    char* ws = (char*)d_ws;
    const size_t partB  = (size_t)NB * TOQ * 32 * 4;      // 2 MB
    const size_t vtB    = (size_t)NB * 64 * 8 * 512 * 2;  // 4 MB
    const size_t elems  = (size_t)NB * TOQ * HD;
    const size_t sbytes = elems * 2;                      // 4 MB per split array
    const size_t ebB    = (size_t)NB * TOQ * TIV * 2;     // 67 MB bf16 E

    float*          recb = (float*)ws;
    float*          part = (float*)(ws + (1 << 16));
    unsigned short* VT   = (unsigned short*)(ws + (1 << 16) + partB);
    const size_t splitOff = (1 << 16) + partB + vtB;
    const size_t ebOff    = splitOff + 4 * sbytes;
    const size_t need2    = ebOff + ebB;                  // ~89.2 MB (proven ok r12)

    if (ws_size >= need2) {
        unsigned short* Qh = (unsigned short*)(ws + splitOff);
        unsigned short* Ql = (unsigned short*)(ws + splitOff + sbytes);
        unsigned short* Vh = (unsigned short*)(ws + splitOff + 2 * sbytes);
        unsigned short* Vl = (unsigned short*)(ws + splitOff + 3 * sbytes);
        unsigned short* Eb = (unsigned short*)(ws + ebOff);
        k0_vtf  <<<dim3(TIV / 64, HD / 64, NB), 256, 0, stream>>>(V, VT);
        k0_split<<<dim3((unsigned)(elems / 8 / 256), 2), 256, 0, stream>>>(Q, V, Qh, Ql, Vh, Vl);
        k1_w8   <<<dim3(TIV / 128, TOQ / 128, NB), 512, 0, stream>>>(Qh, Ql, Vh, Vl, M, Eb, part);
        k2_rowsum<<<dim3(NB * TOQ / 256), 256, 0, stream>>>(part, recb);
        k3_pf   <<<dim3(TOQ / 32, NB), 512, 0, stream>>>(Eb, VT, recb, P, O);
    } else {
        k0_vt_old<<<dim3(TIV / 64, HD / 64, NB), 256, 0, stream>>>(V, VT);
        k1_reg  <<<dim3(TIV / 128, TOQ / 128, NB), 256, 0, stream>>>(Q, V, M, P, part);
        k2_rowsum<<<dim3(NB * TOQ / 256), 256, 0, stream>>>(part, recb);
        k3_pv_old<<<dim3(TOQ / 32, NB), 512, 0, stream>>>(P, VT, recb, O);
    }
}

// Round 15
// 176.784 us; speedup vs baseline: 1.0354x; 1.0282x over previous
//
#include <hip/hip_runtime.h>

#define NB  8
#define TOQ 2048
#define TIV 2048
#define HD  128

typedef float f32x4 __attribute__((ext_vector_type(4)));
typedef short s16x8 __attribute__((ext_vector_type(8)));
typedef unsigned short ushort4v __attribute__((ext_vector_type(4)));
typedef unsigned short ushort8v __attribute__((ext_vector_type(8)));

__device__ __forceinline__ unsigned short f2bf(float f) {   // RNE f32->bf16
    unsigned u = __float_as_uint(f);
    return (unsigned short)((u + 0x7FFFu + ((u >> 16) & 1u)) >> 16);
}
__device__ __forceinline__ float bf2f(unsigned short h) {
    return __uint_as_float(((unsigned)h) << 16);
}

__device__ __forceinline__ void split8(const float4 a, const float4 b,
                                       ushort8v& h, ushort8v& l) {
    const float x[8] = {a.x, a.y, a.z, a.w, b.x, b.y, b.z, b.w};
    #pragma unroll
    for (int j = 0; j < 8; ++j) {
        const unsigned short hi = f2bf(x[j]);
        h[j] = hi;
        l[j] = f2bf(x[j] - bf2f(hi));
    }
}

// async 16B global -> LDS (wave-uniform LDS base + lane*16)
__device__ __forceinline__ void gload16(const void* g, void* l) {
    __builtin_amdgcn_global_load_lds(
        (const __attribute__((address_space(1))) void*)g,
        (__attribute__((address_space(3))) void*)l, 16, 0, 0);
}

// ---------------------------------------------------------------------------
// K0a: elementwise split of Q and V into bf16 hi/lo arrays ([n][row][h]).
// ---------------------------------------------------------------------------
__global__ __launch_bounds__(256) void k0_split(
    const float* __restrict__ Q, const float* __restrict__ V,
    unsigned short* __restrict__ Qh, unsigned short* __restrict__ Ql,
    unsigned short* __restrict__ Vh, unsigned short* __restrict__ Vl)
{
    const size_t i = ((size_t)blockIdx.x * 256 + threadIdx.x) * 8;
    const float* src = blockIdx.y ? V : Q;
    unsigned short* dh = blockIdx.y ? Vh : Qh;
    unsigned short* dl = blockIdx.y ? Vl : Ql;
    const float4 a = *(const float4*)&src[i];
    const float4 b = *(const float4*)&src[i + 4];
    ushort8v h, l;
    split8(a, b, h, l);
    *(ushort8v*)&dh[i] = h;
    *(ushort8v*)&dl[i] = l;
}

// ---------------------------------------------------------------------------
// K0b: VT[n][h][s] = bf16(V[n][s][h])  (4 MB; B-fragment source for k3)
// ---------------------------------------------------------------------------
__global__ __launch_bounds__(256) void k0_vt(
    const float* __restrict__ V, unsigned short* __restrict__ VT)
{
    __shared__ unsigned short tile[64][68];
    const int n  = blockIdx.z;
    const int s0 = blockIdx.x * 64;
    const int h0 = blockIdx.y * 64;
    const int t  = threadIdx.x;

    #pragma unroll
    for (int it = 0; it < 4; ++it) {
        const int f = t + it * 256;
        const int r = f >> 4;
        const int c = f & 15;
        const float4 v = *(const float4*)&V[((size_t)(n * TIV + s0 + r)) * HD + h0 + 4 * c];
        tile[4 * c + 0][r] = f2bf(v.x);
        tile[4 * c + 1][r] = f2bf(v.y);
        tile[4 * c + 2][r] = f2bf(v.z);
        tile[4 * c + 3][r] = f2bf(v.w);
    }
    __syncthreads();

    #pragma unroll
    for (int it = 0; it < 2; ++it) {
        const int f  = t + it * 256;
        const int hh = f >> 3;
        const int sc = f & 7;
        ushort8v o;
        #pragma unroll
        for (int j = 0; j < 8; ++j) o[j] = tile[hh][8 * sc + j];
        *(ushort8v*)&VT[((size_t)(n * HD + h0 + hh)) * TIV + s0 + 8 * sc] = o;
    }
}

// ---------------------------------------------------------------------------
// K1 (tier2, r14-verified): 8-wave transposed QK^T (A=V,B=Q), acc[4][2],
// global_load_lds staging of pre-split arrays, bf16 E out, fused partials.
// ---------------------------------------------------------------------------
__global__ __launch_bounds__(512) void k1_w8(
    const unsigned short* __restrict__ QhG, const unsigned short* __restrict__ QlG,
    const unsigned short* __restrict__ VhG, const unsigned short* __restrict__ VlG,
    const int* __restrict__ M, unsigned short* __restrict__ Eb,
    float* __restrict__ part)
{
    __shared__ unsigned short qh_l[128 * 32], ql_l[128 * 32];
    __shared__ unsigned short vh_l[128 * 32], vl_l[128 * 32];

    const int n    = blockIdx.z;
    const int tt   = blockIdx.y * 128;
    const int ts   = blockIdx.x * 128;
    const int t    = threadIdx.x;
    const int lane = t & 63;
    const int wave = t >> 6;
    const int wr   = wave >> 2;
    const int wc   = wave & 3;
    const int lr   = lane & 15;
    const int kg   = lane >> 4;

    f32x4 acc[4][2];
    #pragma unroll
    for (int i = 0; i < 4; ++i)
        #pragma unroll
        for (int j = 0; j < 2; ++j) acc[i][j] = (f32x4)0.f;

    for (int h0 = 0; h0 < HD; h0 += 32) {
        {
            const int c   = wave * 64 + lane;
            const int row = c >> 2;
            const int kb  = (c & 3) * 8;
            const int lb  = wave * 512;
            const size_t qo = ((size_t)(n * TOQ + tt + row)) * HD + h0 + kb;
            const size_t vo = ((size_t)(n * TIV + ts + row)) * HD + h0 + kb;
            gload16(QhG + qo, qh_l + lb);
            gload16(QlG + qo, ql_l + lb);
            gload16(VhG + vo, vh_l + lb);
            gload16(VlG + vo, vl_l + lb);
        }
        __syncthreads();

        s16x8 aH[4], aL[4];
        #pragma unroll
        for (int fm = 0; fm < 4; ++fm) {
            const int off = (wr * 64 + fm * 16 + lr) * 32 + kg * 8;
            aH[fm] = *(const s16x8*)(vh_l + off);
            aL[fm] = *(const s16x8*)(vl_l + off);
        }
        #pragma unroll
        for (int fn = 0; fn < 2; ++fn) {
            const int off = (wc * 32 + fn * 16 + lr) * 32 + kg * 8;
            const s16x8 bH = *(const s16x8*)(qh_l + off);
            const s16x8 bL = *(const s16x8*)(ql_l + off);
            #pragma unroll
            for (int fm = 0; fm < 4; ++fm) {
                acc[fm][fn] = __builtin_amdgcn_mfma_f32_16x16x32_bf16(aH[fm], bH, acc[fm][fn], 0, 0, 0);
                acc[fm][fn] = __builtin_amdgcn_mfma_f32_16x16x32_bf16(aH[fm], bL, acc[fm][fn], 0, 0, 0);
                acc[fm][fn] = __builtin_amdgcn_mfma_f32_16x16x32_bf16(aL[fm], bH, acc[fm][fn], 0, 0, 0);
            }
        }
        __syncthreads();
    }

    #pragma unroll
    for (int fn = 0; fn < 2; ++fn) {
        const int to_g = tt + wc * 32 + fn * 16 + lr;
        const size_t rowbase = ((size_t)n * TOQ + to_g) * TIV;
        float rs = 0.f;
        #pragma unroll
        for (int fm = 0; fm < 4; ++fm) {
            const int ti_g = ts + wr * 64 + fm * 16 + kg * 4;
            const int4 mv = *(const int4*)&M[rowbase + ti_g];
            float4 e;
            e.x = mv.x ? 0.f : __expf(acc[fm][fn][0]);
            e.y = mv.y ? 0.f : __expf(acc[fm][fn][1]);
            e.z = mv.z ? 0.f : __expf(acc[fm][fn][2]);
            e.w = mv.w ? 0.f : __expf(acc[fm][fn][3]);
            ushort4v eb;
            eb[0] = f2bf(e.x); eb[1] = f2bf(e.y);
            eb[2] = f2bf(e.z); eb[3] = f2bf(e.w);
            *(ushort4v*)&Eb[rowbase + ti_g] = eb;
            rs += (e.x + e.y) + (e.z + e.w);
        }
        rs += __shfl_xor(rs, 16, 64);
        rs += __shfl_xor(rs, 32, 64);
        if (kg == 0)
            part[((size_t)n * TOQ + to_g) * 32 + blockIdx.x * 2 + wr] = rs;
    }
}

// ---------------------------------------------------------------------------
// K1 fallback (register-staged split, f32 E).
// ---------------------------------------------------------------------------
__global__ __launch_bounds__(256) void k1_reg(
    const float* __restrict__ Q, const float* __restrict__ V,
    const int* __restrict__ M, float* __restrict__ E,
    float* __restrict__ part)
{
    __shared__ unsigned short qhi[128 * 32], qlo[128 * 32];
    __shared__ unsigned short vhi[128 * 32], vlo[128 * 32];

    const int n    = blockIdx.z;
    const int tt   = blockIdx.y * 128;
    const int ts   = blockIdx.x * 128;
    const int t    = threadIdx.x;
    const int lane = t & 63;
    const int wave = t >> 6;
    const int wr   = wave >> 1;
    const int wc   = wave & 1;
    const int lr   = lane & 15;
    const int kg   = lane >> 4;

    const float* Qb = Q + ((size_t)n * TOQ + tt) * HD;
    const float* Vb = V + ((size_t)n * TIV + ts) * HD;

    f32x4 acc[4][4];
    #pragma unroll
    for (int i = 0; i < 4; ++i)
        #pragma unroll
        for (int j = 0; j < 4; ++j) acc[i][j] = (f32x4)0.f;

    for (int h0 = 0; h0 < HD; h0 += 32) {
        #pragma unroll
        for (int it = 0; it < 2; ++it) {
            const int i   = t + it * 256;
            const int row = i >> 2;
            const int kb  = i & 3;
            const float* qs = Qb + (size_t)row * HD + h0 + kb * 8;
            const float* vs = Vb + (size_t)row * HD + h0 + kb * 8;
            const float4 q0 = *(const float4*)qs, q1 = *(const float4*)(qs + 4);
            const float4 v0 = *(const float4*)vs, v1 = *(const float4*)(vs + 4);
            ushort8v qh, ql, vh, vl;
            split8(q0, q1, qh, ql);
            split8(v0, v1, vh, vl);
            *(ushort8v*)(qhi + i * 8) = qh;
            *(ushort8v*)(qlo + i * 8) = ql;
            *(ushort8v*)(vhi + i * 8) = vh;
            *(ushort8v*)(vlo + i * 8) = vl;
        }
        __syncthreads();

        s16x8 aH[4], aL[4];
        #pragma unroll
        for (int fm = 0; fm < 4; ++fm) {
            const int off = (wr * 64 + fm * 16 + lr) * 32 + kg * 8;
            aH[fm] = *(const s16x8*)(vhi + off);
            aL[fm] = *(const s16x8*)(vlo + off);
        }
        #pragma unroll
        for (int fn = 0; fn < 4; ++fn) {
            const int off = (wc * 64 + fn * 16 + lr) * 32 + kg * 8;
            const s16x8 bH = *(const s16x8*)(qhi + off);
            const s16x8 bL = *(const s16x8*)(qlo + off);
            #pragma unroll
            for (int fm = 0; fm < 4; ++fm) {
                acc[fm][fn] = __builtin_amdgcn_mfma_f32_16x16x32_bf16(aH[fm], bH, acc[fm][fn], 0, 0, 0);
                acc[fm][fn] = __builtin_amdgcn_mfma_f32_16x16x32_bf16(aH[fm], bL, acc[fm][fn], 0, 0, 0);
                acc[fm][fn] = __builtin_amdgcn_mfma_f32_16x16x32_bf16(aL[fm], bH, acc[fm][fn], 0, 0, 0);
            }
        }
        __syncthreads();
    }

    #pragma unroll
    for (int fn = 0; fn < 4; ++fn) {
        const int to_g = tt + wc * 64 + fn * 16 + lr;
        const size_t rowbase = ((size_t)n * TOQ + to_g) * TIV;
        float rs = 0.f;
        #pragma unroll
        for (int fm = 0; fm < 4; ++fm) {
            const int ti_g = ts + wr * 64 + fm * 16 + kg * 4;
            const int4 mv = *(const int4*)&M[rowbase + ti_g];
            float4 e;
            e.x = mv.x ? 0.f : __expf(acc[fm][fn][0]);
            e.y = mv.y ? 0.f : __expf(acc[fm][fn][1]);
            e.z = mv.z ? 0.f : __expf(acc[fm][fn][2]);
            e.w = mv.w ? 0.f : __expf(acc[fm][fn][3]);
            *(float4*)&E[rowbase + ti_g] = e;
            rs += (e.x + e.y) + (e.z + e.w);
        }
        rs += __shfl_xor(rs, 16, 64);
        rs += __shfl_xor(rs, 32, 64);
        if (kg == 0)
            part[((size_t)n * TOQ + to_g) * 32 + blockIdx.x * 2 + wr] = rs;
    }
}

// ---------------------------------------------------------------------------
// K2: rec[row] = 1 / sum of 32 partials
// ---------------------------------------------------------------------------
__global__ __launch_bounds__(256) void k2_rowsum(
    const float* __restrict__ part, float* __restrict__ rec)
{
    const int row = blockIdx.x * 256 + threadIdx.x;
    const float4* p4 = (const float4*)(part + (size_t)row * 32);
    float s = 0.f;
    #pragma unroll
    for (int i = 0; i < 8; ++i) {
        const float4 v = p4[i];
        s += (v.x + v.y) + (v.z + v.w);
    }
    rec[row] = 1.f / s;
}

// ---------------------------------------------------------------------------
// K3 (tier2): MAX-OCCUPANCY PV.  16-row tiles -> 1024 blocks (4 blocks/CU,
// 32 waves/CU).  8 waves = 8 k-eighths (256 cols) of the SAME 16 rows; r12's
// verified main loop (bf16 E, scattered VT gathers, fire-and-forget f32 P).
// Epilogue: 3-round binary-tree reduction in a 4-slot LDS buffer (33.8 KB so
// LDS permits 4 blocks/CU).
// ---------------------------------------------------------------------------
__global__ __launch_bounds__(512) void k3_occ(
    const unsigned short* __restrict__ Eb, const unsigned short* __restrict__ VT,
    const float* __restrict__ rec, float* __restrict__ P, float* __restrict__ O)
{
    __shared__ float red[4][16][132];              // 33792 B

    const int n    = blockIdx.y;
    const int r0   = blockIdx.x * 16;
    const int t    = threadIdx.x;
    const int q    = t >> 6;                       // k-eighth 0..7
    const int lane = t & 63;
    const int lr   = lane & 15;                    // row (A) / col (B,D)
    const int kg   = lane >> 4;

    const int rowg = r0 + lr;
    const float rc = rec[n * TOQ + rowg];
    const unsigned short* Erow = Eb + ((size_t)n * TOQ + rowg) * TIV;
    float* Prow = P + ((size_t)n * TOQ + rowg) * TIV;
    const unsigned short* VTb = VT + (size_t)n * HD * TIV;

    f32x4 acc[8];
    #pragma unroll
    for (int fn = 0; fn < 8; ++fn) acc[fn] = (f32x4)0.f;

    const int kbase = q * 256 + kg * 8;

    #pragma unroll 2
    for (int k0 = 0; k0 < 256; k0 += 32) {
        const int k = kbase + k0;
        const ushort8v ev = *(const ushort8v*)&Erow[k];
        float pv[8];
        #pragma unroll
        for (int j = 0; j < 8; ++j) pv[j] = bf2f(ev[j]) * rc;

        float4 p0, p1;
        p0.x = pv[0]; p0.y = pv[1]; p0.z = pv[2]; p0.w = pv[3];
        p1.x = pv[4]; p1.y = pv[5]; p1.z = pv[6]; p1.w = pv[7];
        *(float4*)&Prow[k]     = p0;               // P output (disjoint buffer)
        *(float4*)&Prow[k + 4] = p1;

        s16x8 a;
        #pragma unroll
        for (int j = 0; j < 8; ++j) a[j] = (short)f2bf(pv[j]);

        #pragma unroll
        for (int fn = 0; fn < 8; ++fn) {
            const s16x8 b = *(const s16x8*)&VTb[(size_t)(fn * 16 + lr) * TIV + k];
            acc[fn] = __builtin_amdgcn_mfma_f32_16x16x32_bf16(a, b, acc[fn], 0, 0, 0);
        }
    }

    // --- tree reduction 8 -> 4 -> 2 -> 1 ------------------------------------
    #define PARK(slot)                                                         \
        _Pragma("unroll") for (int fn = 0; fn < 8; ++fn)                       \
        _Pragma("unroll") for (int ri = 0; ri < 4; ++ri)                       \
            red[slot][kg * 4 + ri][fn * 16 + lr] = acc[fn][ri];
    #define GATHER(slot)                                                       \
        _Pragma("unroll") for (int fn = 0; fn < 8; ++fn)                       \
        _Pragma("unroll") for (int ri = 0; ri < 4; ++ri)                       \
            acc[fn][ri] += red[slot][kg * 4 + ri][fn * 16 + lr];

    if (q & 1) { PARK(q >> 1) }                    // 1,3,5,7 -> slots 0..3
    __syncthreads();
    if (!(q & 1)) { GATHER(q >> 1) }               // 0,2,4,6 add
    __syncthreads();
    if (!(q & 1) && (q & 2)) { PARK(q >> 2) }      // 2,6 -> slots 0,1
    __syncthreads();
    if (!(q & 3)) { GATHER(q >> 2) }               // 0,4 add
    __syncthreads();
    if (q == 4) { PARK(0) }                        // 4 -> slot 0
    __syncthreads();
    if (q == 0) {
        GATHER(0)
        #pragma unroll
        for (int fn = 0; fn < 8; ++fn) {
            #pragma unroll
            for (int ri = 0; ri < 4; ++ri) {
                const int orow = r0 + kg * 4 + ri;
                O[((size_t)n * TOQ + orow) * HD + fn * 16 + lr] = acc[fn][ri];
            }
        }
    }
    #undef PARK
    #undef GATHER
}

// ---------------------------------------------------------------------------
// K3 fallback (r11 verbatim): in-place f32 E->P, 32-row tiles.
// ---------------------------------------------------------------------------
__global__ __launch_bounds__(512) void k3_pv_old(
    float* __restrict__ EP, const unsigned short* __restrict__ VT,
    const float* __restrict__ rec, float* __restrict__ O)
{
    __shared__ float red[2][3][16][132];

    const int n    = blockIdx.y;
    const int r0   = blockIdx.x * 32;
    const int t    = threadIdx.x;
    const int wave = t >> 6;
    const int lane = t & 63;
    const int p    = wave >> 2;
    const int q    = wave & 3;
    const int lr   = lane & 15;
    const int kg   = lane >> 4;

    const int rowg = r0 + p * 16 + lr;
    const float rc = rec[n * TOQ + rowg];
    float* Erow = EP + ((size_t)n * TOQ + rowg) * TIV;
    const unsigned short* VTb = VT + (size_t)n * HD * TIV;

    f32x4 acc[8];
    #pragma unroll
    for (int fn = 0; fn < 8; ++fn) acc[fn] = (f32x4)0.f;

    const int kbase = q * 512 + kg * 8;

    #pragma unroll 2
    for (int k0 = 0; k0 < 512; k0 += 32) {
        const int k = kbase + k0;
        const float4 e0 = *(const float4*)&Erow[k];
        const float4 e1 = *(const float4*)&Erow[k + 4];
        float4 p0, p1;
        p0.x = e0.x * rc; p0.y = e0.y * rc; p0.z = e0.z * rc; p0.w = e0.w * rc;
        p1.x = e1.x * rc; p1.y = e1.y * rc; p1.z = e1.z * rc; p1.w = e1.w * rc;
        *(float4*)&Erow[k]     = p0;
        *(float4*)&Erow[k + 4] = p1;

        s16x8 a;
        a[0] = (short)f2bf(p0.x); a[1] = (short)f2bf(p0.y);
        a[2] = (short)f2bf(p0.z); a[3] = (short)f2bf(p0.w);
        a[4] = (short)f2bf(p1.x); a[5] = (short)f2bf(p1.y);
        a[6] = (short)f2bf(p1.z); a[7] = (short)f2bf(p1.w);

        #pragma unroll
        for (int fn = 0; fn < 8; ++fn) {
            const s16x8 b = *(const s16x8*)&VTb[(size_t)(fn * 16 + lr) * TIV + k];
            acc[fn] = __builtin_amdgcn_mfma_f32_16x16x32_bf16(a, b, acc[fn], 0, 0, 0);
        }
    }

    if (q != 0) {
        #pragma unroll
        for (int fn = 0; fn < 8; ++fn)
            #pragma unroll
            for (int ri = 0; ri < 4; ++ri)
                red[p][q - 1][kg * 4 + ri][fn * 16 + lr] = acc[fn][ri];
    }
    __syncthreads();
    if (q == 0) {
        #pragma unroll
        for (int fn = 0; fn < 8; ++fn) {
            #pragma unroll
            for (int ri = 0; ri < 4; ++ri) {
                const int orow = r0 + p * 16 + kg * 4 + ri;
                float o = acc[fn][ri];
                o += red[p][0][kg * 4 + ri][fn * 16 + lr];
                o += red[p][1][kg * 4 + ri][fn * 16 + lr];
                o += red[p][2][kg * 4 + ri][fn * 16 + lr];
                O[((size_t)n * TOQ + orow) * HD + fn * 16 + lr] = o;
            }
        }
    }
}

// ---------------------------------------------------------------------------
extern "C" void kernel_launch(void* const* d_in, const int* in_sizes, int n_in,
                              void* d_out, int out_size, void* d_ws, size_t ws_size,
                              hipStream_t stream)
{
    const float* Q = (const float*)d_in[0];
    const float* V = (const float*)d_in[1];
    const int*   M = (const int*)d_in[2];

    float* O = (float*)d_out;                         // [8][2048][128] f32
    float* P = O + (size_t)NB * TOQ * HD;             // [8][2048][2048] f32

    char* ws = (char*)d_ws;
    const size_t partB  = (size_t)NB * TOQ * 32 * 4;      // 2 MB
    const size_t vtB    = (size_t)NB * HD * TIV * 2;      // 4 MB
    const size_t elems  = (size_t)NB * TOQ * HD;
    const size_t sbytes = elems * 2;                      // 4 MB per split array
    const size_t ebB    = (size_t)NB * TOQ * TIV * 2;     // 67 MB bf16 E

    float*          recb = (float*)ws;
    float*          part = (float*)(ws + (1 << 16));
    unsigned short* VT   = (unsigned short*)(ws + (1 << 16) + partB);
    const size_t splitOff = (1 << 16) + partB + vtB;
    const size_t ebOff    = splitOff + 4 * sbytes;
    const size_t need2    = ebOff + ebB;                  // ~89.2 MB (proven r12/r14)

    k0_vt<<<dim3(TIV / 64, HD / 64, NB), 256, 0, stream>>>(V, VT);

    if (ws_size >= need2) {
        unsigned short* Qh = (unsigned short*)(ws + splitOff);
        unsigned short* Ql = (unsigned short*)(ws + splitOff + sbytes);
        unsigned short* Vh = (unsigned short*)(ws + splitOff + 2 * sbytes);
        unsigned short* Vl = (unsigned short*)(ws + splitOff + 3 * sbytes);
        unsigned short* Eb = (unsigned short*)(ws + ebOff);
        k0_split<<<dim3((unsigned)(elems / 8 / 256), 2), 256, 0, stream>>>(Q, V, Qh, Ql, Vh, Vl);
        k1_w8   <<<dim3(TIV / 128, TOQ / 128, NB), 512, 0, stream>>>(Qh, Ql, Vh, Vl, M, Eb, part);
        k2_rowsum<<<dim3(NB * TOQ / 256), 256, 0, stream>>>(part, recb);
        k3_occ  <<<dim3(TOQ / 16, NB), 512, 0, stream>>>(Eb, VT, recb, P, O);
    } else {
        k1_reg  <<<dim3(TIV / 128, TOQ / 128, NB), 256, 0, stream>>>(Q, V, M, P, part);
        k2_rowsum<<<dim3(NB * TOQ / 256), 256, 0, stream>>>(part, recb);
        k3_pv_old<<<dim3(TOQ / 32, NB), 512, 0, stream>>>(P, VT, recb, O);
    }
}